// Round 2
// baseline (147.098 us; speedup 1.0000x reference)
//
#include <hip/hip_runtime.h>

// GeodesicLoss: reference's velocity starts at exactly zero, so
// acc = -einsum(Gamma, v, v) == 0 every step and traj == outputs identically.
// Answer = mean_b ||outputs[b] - targets[b]||_2, B=524288, D=32.
// christoffel_symbols (d_in[2]) is mathematically dead.
//
// R5 theory: sched_barrier(0) failed to pin the loads (VGPR=20 proves the
// IR-level sink: llvm.amdgcn.sched.barrier doesn't write memory, so mid-end
// passes sank the global loads past it before the machine scheduler ran).
// Fix: bind ALL 16 float4 load results to ONE asm volatile via "+v" tuple
// operands. Data dependence makes the sink impossible at every level, forces
// a single waitcnt point, and keeps 64 data VGPRs live -> 16 KB MLP/wave.
// Also: no LDS, no barrier, no early-exit waves. Each wave owns 512
// consecutive float4 (64 rows); row-of-8 reduce via 3-step shfl_xor.

typedef float vf4 __attribute__((ext_vector_type(4)));

static constexpr int B_ROWS        = 524288;
static constexpr int THREADS       = 256;
static constexpr int WAVES_PER_BLK = THREADS / 64;
static constexpr int F4_PER_WAVE   = 512;                   // 8 k-slots x 64 lanes
static constexpr int TOTAL_F4      = B_ROWS * 8;            // 4,194,304 float4/array
static constexpr int NUM_BLOCKS    = TOTAL_F4 / (F4_PER_WAVE * WAVES_PER_BLK); // 2048
static constexpr int NUM_PARTIALS  = NUM_BLOCKS * WAVES_PER_BLK;               // 8192

__global__ __launch_bounds__(256) void geodesic_main(
    const vf4* __restrict__ o4,
    const vf4* __restrict__ t4,
    float* __restrict__ ws)
{
    const int t    = threadIdx.x;
    const int wave = t >> 6;
    const int lane = t & 63;
    const int wgid = blockIdx.x * WAVES_PER_BLK + wave;
    const int base = wgid * F4_PER_WAVE + lane;             // < 4.19M, fits int

    // 16 independent, perfectly coalesced 16B loads (1 KiB/wave/instr).
    vf4 o0 = o4[base +   0], o1 = o4[base +  64], o2 = o4[base + 128], o3 = o4[base + 192];
    vf4 o4r= o4[base + 256], o5 = o4[base + 320], o6 = o4[base + 384], o7 = o4[base + 448];
    vf4 g0 = t4[base +   0], g1 = t4[base +  64], g2 = t4[base + 128], g3 = t4[base + 192];
    vf4 g4 = t4[base + 256], g5 = t4[base + 320], g6 = t4[base + 384], g7 = t4[base + 448];

    // Single pin point: every load's ONLY first consumer is this volatile asm.
    // No IR pass can sink a load past its consumer; one waitcnt, 64 VGPRs live.
    asm volatile("" :
        "+v"(o0), "+v"(o1), "+v"(o2), "+v"(o3),
        "+v"(o4r), "+v"(o5), "+v"(o6), "+v"(o7),
        "+v"(g0), "+v"(g1), "+v"(g2), "+v"(g3),
        "+v"(g4), "+v"(g5), "+v"(g6), "+v"(g7));

    const bool lead = (lane & 7) == 0;
    float acc = 0.0f;

    vf4 ov[8] = { o0, o1, o2, o3, o4r, o5, o6, o7 };
    vf4 gv[8] = { g0, g1, g2, g3, g4,  g5, g6, g7 };
#pragma unroll
    for (int k = 0; k < 8; ++k) {
        float dx = ov[k][0] - gv[k][0];
        float dy = ov[k][1] - gv[k][1];
        float dz = ov[k][2] - gv[k][2];
        float dw = ov[k][3] - gv[k][3];
        float p  = dx * dx + dy * dy + dz * dz + dw * dw;
        // 8 consecutive lanes hold the 8 chunks of one row (D=32 floats).
        p += __shfl_xor(p, 1);
        p += __shfl_xor(p, 2);
        p += __shfl_xor(p, 4);
        float r = sqrtf(p);
        acc += lead ? r : 0.0f;                             // predicated, no branch
    }

    // Only lanes 0,8,...,56 hold row distances; 3 xor steps fold them to lane 0.
    acc += __shfl_xor(acc, 8);
    acc += __shfl_xor(acc, 16);
    acc += __shfl_xor(acc, 32);
    if (lane == 0) ws[wgid] = acc;                          // per-wave partial
}

__global__ __launch_bounds__(256) void geodesic_finish(
    const vf4* __restrict__ ws4,                            // 8192 floats = 2048 vf4
    float* __restrict__ out)
{
    const int t = threadIdx.x;
    float s = 0.0f;
#pragma unroll
    for (int k = 0; k < 8; ++k) {
        vf4 v = ws4[k * 256 + t];
        s += (v[0] + v[1]) + (v[2] + v[3]);
    }
    s += __shfl_xor(s, 1);
    s += __shfl_xor(s, 2);
    s += __shfl_xor(s, 4);
    s += __shfl_xor(s, 8);
    s += __shfl_xor(s, 16);
    s += __shfl_xor(s, 32);

    __shared__ float sm[4];
    if ((t & 63) == 0) sm[t >> 6] = s;
    __syncthreads();
    if (t == 0) {
        out[0] = ((sm[0] + sm[1]) + (sm[2] + sm[3])) * (1.0f / (float)B_ROWS);
    }
}

extern "C" void kernel_launch(void* const* d_in, const int* in_sizes, int n_in,
                              void* d_out, int out_size, void* d_ws, size_t ws_size,
                              hipStream_t stream) {
    const vf4* outputs = (const vf4*)d_in[0];
    const vf4* targets = (const vf4*)d_in[1];
    // d_in[2] (christoffel_symbols) unused: velocity is identically zero.
    float* ws  = (float*)d_ws;                              // 8192 floats (32 KiB)
    float* out = (float*)d_out;

    // No memset needed: geodesic_finish writes out[0] unconditionally.
    geodesic_main<<<dim3(NUM_BLOCKS), dim3(THREADS), 0, stream>>>(outputs, targets, ws);
    geodesic_finish<<<dim3(1), dim3(THREADS), 0, stream>>>((const vf4*)ws, out);
}

// Round 4
// 145.585 us; speedup vs baseline: 1.0104x; 1.0104x over previous
//
#include <hip/hip_runtime.h>

// GeodesicLoss: reference's velocity starts at exactly zero, so
// acc = -einsum(Gamma, v, v) == 0 every step and traj == outputs identically.
// Answer = mean_b ||outputs[b] - targets[b]||_2, B=524288, D=32.
// christoffel_symbols (d_in[2]) is mathematically dead.
//
// R7 = R6 retry (container failed twice = infra; no counters returned).
// Hardening: "=&v" early-clobber on all load outputs so the allocator can
// never overlap a load destination with the address pair of a later
// program-ordered volatile load.
//
// Probe design (unchanged): three prior variants (LDS-transpose, compiler-
// scheduled, single-asm-pin) all measured 3.15 TB/s read (134MB/42.6us) ==
// m13 copy's read component. Last confound: all were burst-then-drain.
// This hand-writes the canonical stream:
//   - 16 volatile inline-asm global_load_dwordx4 (fixed order, un-sinkable)
//   - staged counted drain: s_waitcnt vmcnt(12/8/4/0); compute overlaps the
//     still-outstanding loads (AITER pattern; hipcc never emits this)
//   - sched_barrier(0) after each waitcnt (rule #18: hipcc hoists reg-only
//     ops past inline-asm waitcnts despite data deps)
// If this doesn't beat ~43us, the ~3.2 TB/s pure-read ceiling is real.

typedef float vf4 __attribute__((ext_vector_type(4)));

static constexpr int B_ROWS     = 524288;
static constexpr int THREADS    = 256;
static constexpr int NUM_BLOCKS = 2048;   // 8192 waves

__global__ __launch_bounds__(256) void geodesic_main(
    const float* __restrict__ op,
    const float* __restrict__ tp,
    float* __restrict__ ws)
{
    const int t    = threadIdx.x;
    const int wave = t >> 6;
    const int lane = t & 63;
    const int w    = blockIdx.x * 4 + wave;

    // Lane's first float4, as a byte offset. Wave covers f4 [w*512, w*512+512)
    // per array; load k hits f4 index w*512 + k*64 + lane  (k = 0..7).
    const unsigned long long fbyte = ((unsigned long long)w * 512 + lane) * 16ull;
    unsigned long long oA = (unsigned long long)op + fbyte;   // k=0..3 via offset:k*1024
    unsigned long long oB = oA + 4096ull;                     // k=4..7
    unsigned long long tA = (unsigned long long)tp + fbyte;
    unsigned long long tB = tA + 4096ull;

    vf4 o0, o1, o2, o3, o4v, o5, o6, o7;
    vf4 g0, g1, g2, g3, g4,  g5, g6, g7;

    // Fixed issue order (volatile asms keep program order among themselves):
    // groups of 4 = [o,o,g,g], drained group-by-group below.
    asm volatile("global_load_dwordx4 %0, %1, off"             : "=&v"(o0)  : "v"(oA));
    asm volatile("global_load_dwordx4 %0, %1, off offset:1024" : "=&v"(o1)  : "v"(oA));
    asm volatile("global_load_dwordx4 %0, %1, off"             : "=&v"(g0)  : "v"(tA));
    asm volatile("global_load_dwordx4 %0, %1, off offset:1024" : "=&v"(g1)  : "v"(tA));
    asm volatile("global_load_dwordx4 %0, %1, off offset:2048" : "=&v"(o2)  : "v"(oA));
    asm volatile("global_load_dwordx4 %0, %1, off offset:3072" : "=&v"(o3)  : "v"(oA));
    asm volatile("global_load_dwordx4 %0, %1, off offset:2048" : "=&v"(g2)  : "v"(tA));
    asm volatile("global_load_dwordx4 %0, %1, off offset:3072" : "=&v"(g3)  : "v"(tA));
    asm volatile("global_load_dwordx4 %0, %1, off"             : "=&v"(o4v) : "v"(oB));
    asm volatile("global_load_dwordx4 %0, %1, off offset:1024" : "=&v"(o5)  : "v"(oB));
    asm volatile("global_load_dwordx4 %0, %1, off"             : "=&v"(g4)  : "v"(tB));
    asm volatile("global_load_dwordx4 %0, %1, off offset:1024" : "=&v"(g5)  : "v"(tB));
    asm volatile("global_load_dwordx4 %0, %1, off offset:2048" : "=&v"(o6)  : "v"(oB));
    asm volatile("global_load_dwordx4 %0, %1, off offset:3072" : "=&v"(o7)  : "v"(oB));
    asm volatile("global_load_dwordx4 %0, %1, off offset:2048" : "=&v"(g6)  : "v"(tB));
    asm volatile("global_load_dwordx4 %0, %1, off offset:3072" : "=&v"(g7)  : "v"(tB));

    const bool lead = (lane & 7) == 0;
    float acc = 0.0f;

    // 8 consecutive lanes hold the 8 chunks of one row (D = 32 floats).
#define PROC(ov, gv) do {                                              \
        float dx_ = (ov)[0] - (gv)[0], dy_ = (ov)[1] - (gv)[1];        \
        float dz_ = (ov)[2] - (gv)[2], dw_ = (ov)[3] - (gv)[3];        \
        float p_  = dx_*dx_ + dy_*dy_ + dz_*dz_ + dw_*dw_;             \
        p_ += __shfl_xor(p_, 1);                                       \
        p_ += __shfl_xor(p_, 2);                                       \
        p_ += __shfl_xor(p_, 4);                                       \
        acc += lead ? sqrtf(p_) : 0.0f;                                \
    } while (0)

    asm volatile("s_waitcnt vmcnt(12)");      // o0,o1,g0,g1 landed; 12 in flight
    __builtin_amdgcn_sched_barrier(0);
    PROC(o0, g0);
    PROC(o1, g1);

    asm volatile("s_waitcnt vmcnt(8)");       // +o2,o3,g2,g3; 8 in flight
    __builtin_amdgcn_sched_barrier(0);
    PROC(o2, g2);
    PROC(o3, g3);

    asm volatile("s_waitcnt vmcnt(4)");       // +o4,o5,g4,g5; 4 in flight
    __builtin_amdgcn_sched_barrier(0);
    PROC(o4v, g4);
    PROC(o5, g5);

    asm volatile("s_waitcnt vmcnt(0)");       // all landed
    __builtin_amdgcn_sched_barrier(0);
    PROC(o6, g6);
    PROC(o7, g7);
#undef PROC

    // Lanes 0,8,...,56 hold row distances; fold to lane 0, one partial/wave.
    acc += __shfl_xor(acc, 8);
    acc += __shfl_xor(acc, 16);
    acc += __shfl_xor(acc, 32);
    if (lane == 0) ws[w] = acc;
}

__global__ __launch_bounds__(256) void geodesic_finish(
    const vf4* __restrict__ ws4,              // 8192 floats = 2048 vf4
    float* __restrict__ out)
{
    const int t = threadIdx.x;
    float s = 0.0f;
#pragma unroll
    for (int k = 0; k < 8; ++k) {
        vf4 v = ws4[k * 256 + t];
        s += (v[0] + v[1]) + (v[2] + v[3]);
    }
    s += __shfl_xor(s, 1);
    s += __shfl_xor(s, 2);
    s += __shfl_xor(s, 4);
    s += __shfl_xor(s, 8);
    s += __shfl_xor(s, 16);
    s += __shfl_xor(s, 32);

    __shared__ float sm[4];
    if ((t & 63) == 0) sm[t >> 6] = s;
    __syncthreads();
    if (t == 0) {
        out[0] = ((sm[0] + sm[1]) + (sm[2] + sm[3])) * (1.0f / (float)B_ROWS);
    }
}

extern "C" void kernel_launch(void* const* d_in, const int* in_sizes, int n_in,
                              void* d_out, int out_size, void* d_ws, size_t ws_size,
                              hipStream_t stream) {
    const float* outputs = (const float*)d_in[0];
    const float* targets = (const float*)d_in[1];
    // d_in[2] (christoffel_symbols) unused: velocity is identically zero.
    float* ws  = (float*)d_ws;                // 8192 floats (32 KiB)
    float* out = (float*)d_out;

    // No memset needed: geodesic_finish writes out[0] unconditionally.
    geodesic_main<<<dim3(NUM_BLOCKS), dim3(THREADS), 0, stream>>>(outputs, targets, ws);
    geodesic_finish<<<dim3(1), dim3(THREADS), 0, stream>>>((const vf4*)ws, out);
}